// Round 9
// baseline (6652.572 us; speedup 1.0000x reference)
//
#include <hip/hip_runtime.h>

// FPS: 2 batches x 131072 pts, 4096 samples/batch, seed = point 0.
// EXACT certified lookahead FPS, v4: EXACT extraction (r8's pipelined
// extraction inflated the cutoff and halved certified depth - reverted),
// KW=32 wave candidates, 8B keys, batched sys-scope rendezvous, tiered
// register sim.
//
// Evidence r0-r8: sys-scope rendezvous RT ~2.5-3us is the hard floor
// (sc0 never resolves cross-CU on this part, r0-r4); lookahead amortizes
// it (r5: 6951, r6: 3667 @ KW=8, j~8); r8's stale-extraction pipeline
// raised the cutoff one round behind -> j~4.5 -> 5396us. Depth tracks
// KW, so v4 doubles depth and pays one serial store-flight per round.
//
// Per rendezvous round r (all 32 blocks of a batch):
//  1. EXTRACT (exact dists): per-lane Batcher-16 sort (63 CEs, compile-
//     time indices -> registers), then 32 DPP-tournament pops over lane
//     heads; winner lane shifts its sorted list. Pop c lands in ship
//     quad of lane c>>1 (half c&1). cand 31 == wave's 32nd best.
//     Key = dist_bits<<32 | r<<17 | (0x1FFFF - idx): u64 order ==
//     (dist desc, idx asc) == jnp.argmax first-index tiebreak.
//  2. SHIP: lanes 0..15 store one dwordx4 (2 cands), sys scope, unacked.
//     POLL: 8 batched dwordx4/lane (ONE vmcnt RT) covers the wave's
//     1024-cand quarter; all-sys scope; s_sleep backoff after 2 tries.
//  3. CUTOFF = max over 128 wave-slots of 32nd-best key, read straight
//     from poll regs (lanes L&15==15 hold 8 wave-slots' cand-31 each).
//     Exact keys => any unshipped point key < its wave's 32nd <= cutk.
//  4. PRUNE: keys > cutk -> wave-aggregated LDS append (pool set is
//     block-identical; order irrelevant, winners found by u64 max).
//  5. SIM: certified loop, FULL-KEY test wk > cutk every step. t=0 is
//     GUARANTEED (global max = some wave's exact top-1, in pool; unique
//     keys => strictly > cutk) => j>=1, no livelock. Register tier
//     NC=4/8/16 (m<=256/512/1024, no barriers) else block tier
//     (16/thread, block_max per step, m<=4096=pool cap).
//  6. COMMIT: rank0 wave0 writes rows S+1..S+j; ALL blocks min-update
//     their 4096 register dists per winner in ascending order (exact
//     reference fp sequence => bit-exact; winner coords re-read from
//     cached pts[idx]).
//
// Ring safety (RING=2): a wave ships round r+1 (overwriting slot r-1)
// only after its poll(r) passed, which requires ALL 128 waves stored r,
// each after its poll(r-1) finished reading slot r-1. Tags: bits 17-31
// of each cand's lo word == r; zeroed/stale slots never match (1 <= r
// <= 4095 < 2^15 since j>=1 every round).

#define NB    32
#define TPB   256
#define PPT   16
#define NPB   131072
#define MSAMP 4096
#define RING  2
#define KW    32
#define NWAVE 128
#define NCAND (NWAVE * KW)      // 4096 candidates / round / batch
#define RBU32 (NCAND * 2)       // 8192 u32 = 32KB per ring slot
#define JCAP  64

typedef unsigned long long u64;
typedef unsigned int u32;
typedef __attribute__((ext_vector_type(4))) u32 u32x4;

__device__ __forceinline__ void st16_sys(u32* p, u32x4 v) {
  asm volatile("global_store_dwordx4 %0, %1, off sc0 sc1"
               :: "v"(p), "v"(v) : "memory");
}
// 8 poll loads issued back-to-back, ONE vmcnt drain (single RT).
__device__ __forceinline__ void ld16x8_sys(
    const u32* p0, const u32* p1, const u32* p2, const u32* p3,
    const u32* p4, const u32* p5, const u32* p6, const u32* p7,
    u32x4& q0, u32x4& q1, u32x4& q2, u32x4& q3,
    u32x4& q4, u32x4& q5, u32x4& q6, u32x4& q7) {
  asm volatile(
    "global_load_dwordx4 %0, %8, off sc0 sc1\n\t"
    "global_load_dwordx4 %1, %9, off sc0 sc1\n\t"
    "global_load_dwordx4 %2, %10, off sc0 sc1\n\t"
    "global_load_dwordx4 %3, %11, off sc0 sc1\n\t"
    "global_load_dwordx4 %4, %12, off sc0 sc1\n\t"
    "global_load_dwordx4 %5, %13, off sc0 sc1\n\t"
    "global_load_dwordx4 %6, %14, off sc0 sc1\n\t"
    "global_load_dwordx4 %7, %15, off sc0 sc1\n\t"
    "s_waitcnt vmcnt(0)"
    : "=v"(q0), "=v"(q1), "=v"(q2), "=v"(q3),
      "=v"(q4), "=v"(q5), "=v"(q6), "=v"(q7)
    : "v"(p0), "v"(p1), "v"(p2), "v"(p3),
      "v"(p4), "v"(p5), "v"(p6), "v"(p7)
    : "memory");
}

// ---- DPP helpers (proven r2-r8) ---------------------------------------
template<int CTRL>
__device__ __forceinline__ u64 dpp_move64(u64 x) {
  int lo = (int)(u32)(x & 0xFFFFFFFFull);
  int hi = (int)(u32)(x >> 32);
  int nlo = __builtin_amdgcn_update_dpp(lo, lo, CTRL, 0xF, 0xF, false);
  int nhi = __builtin_amdgcn_update_dpp(hi, hi, CTRL, 0xF, 0xF, false);
  return ((u64)(u32)nhi << 32) | (u64)(u32)nlo;
}
#define DPP_ROW_SHR(n)  (0x110 + (n))
#define DPP_BCAST15     0x142
#define DPP_BCAST31     0x143

__device__ __forceinline__ u64 dpp_max64_to63(u64 k) {
  u64 t;
  t = dpp_move64<DPP_ROW_SHR(1)>(k); if (t > k) k = t;
  t = dpp_move64<DPP_ROW_SHR(2)>(k); if (t > k) k = t;
  t = dpp_move64<DPP_ROW_SHR(4)>(k); if (t > k) k = t;
  t = dpp_move64<DPP_ROW_SHR(8)>(k); if (t > k) k = t;
  t = dpp_move64<DPP_BCAST15>(k);    if (t > k) k = t;
  t = dpp_move64<DPP_BCAST31>(k);    if (t > k) k = t;
  return k;                                   // lane63 = wave max
}
__device__ __forceinline__ u64 bcast_key(u64 k, int srclane) {
  u32 lo = (u32)__builtin_amdgcn_readlane((int)(u32)(k & 0xFFFFFFFFull), srclane);
  u32 hi = (u32)__builtin_amdgcn_readlane((int)(u32)(k >> 32), srclane);
  return ((u64)hi << 32) | (u64)lo;
}
__device__ __forceinline__ float bcast_f32(float v, int srclane) {
  return __uint_as_float((u32)__builtin_amdgcn_readlane((int)__float_as_uint(v), srclane));
}

struct BMax { u64 k; float x, y, z; };
__device__ __forceinline__ BMax block_max(u64 tk, float tx, float ty, float tz,
    int lane, int wv, int sb,
    u64* s_key, float* s_cx, float* s_cy, float* s_cz) {
  u64 wk = bcast_key(dpp_max64_to63(tk), 63);
  int wl = __ffsll(__ballot(tk == wk)) - 1;
  float wx = bcast_f32(tx, wl), wy = bcast_f32(ty, wl), wz = bcast_f32(tz, wl);
  if (lane == 0) { s_key[sb+wv]=wk; s_cx[sb+wv]=wx; s_cy[sb+wv]=wy; s_cz[sb+wv]=wz; }
  __syncthreads();
  u64 k0=s_key[sb],k1=s_key[sb+1],k2=s_key[sb+2],k3=s_key[sb+3];
  int bi=sb; u64 bk=k0;
  if (k1>bk){bk=k1;bi=sb+1;}
  if (k2>bk){bk=k2;bi=sb+2;}
  if (k3>bk){bk=k3;bi=sb+3;}
  BMax r; r.k=bk; r.x=s_cx[bi]; r.y=s_cy[bi]; r.z=s_cz[bi];
  return r;
}

// ---- wave-register sim (exact pool; full-key certified loop) ----------
template<int NC>
__device__ __forceinline__ int sim_wave(const u64* s_pool, int m, u64 cutk,
    int jmax, int lane, const float4* bpts,
    float& ox, float& oy, float& oz)
{
#pragma clang fp contract(off)
  u64 ck[NC]; float cx[NC], cy[NC], cz[NC];
#pragma unroll
  for (int i = 0; i < NC; ++i) {
    int idx = lane + i * 64;
    bool v = idx < m;
    u64 k = v ? s_pool[idx] : 0ull;
    int gi = v ? (int)(0x1FFFFu - (u32)(k & 0x1FFFFull)) : 0;
    float4 c = bpts[gi];
    ck[i] = k; cx[i] = c.y; cy[i] = c.z; cz[i] = c.w;
  }
  int j = 0;
  for (int t = 0; t < jmax; ++t) {
    u64 tk = ck[0]; float mx = cx[0], my = cy[0], mz = cz[0];
#pragma unroll
    for (int i = 1; i < NC; ++i)
      if (ck[i] > tk) { tk = ck[i]; mx = cx[i]; my = cy[i]; mz = cz[i]; }
    u64 wk = bcast_key(dpp_max64_to63(tk), 63);
    if (wk <= cutk) break;                   // full-key cert (t=0 never fails)
    int wl = __ffsll(__ballot(tk == wk)) - 1;
    float wx = bcast_f32(mx, wl), wy = bcast_f32(my, wl), wz = bcast_f32(mz, wl);
    if (lane == t) { ox = wx; oy = wy; oz = wz; }
    j = t + 1;
#pragma unroll
    for (int i = 0; i < NC; ++i) {
      float dx = cx[i]-wx, dy = cy[i]-wy, dz = cz[i]-wz;
      float d2 = __fadd_rn(__fadd_rn(__fmul_rn(dx,dx), __fmul_rn(dy,dy)),
                           __fmul_rn(dz,dz));
      float nd = fminf(__uint_as_float((u32)(ck[i] >> 32)), d2);
      ck[i] = ((u64)__float_as_uint(nd) << 32) | (ck[i] & 0xFFFFFFFFull);
    }
  }
  return j;
}

// ---- block LDS sim (m <= 4096 = pool cap; exact) ----------------------
__device__ __forceinline__ int sim_block(const u64* s_pool, int m, u64 cutk,
    int jmax, int tid, int lane, int wv, int& sb, const float4* bpts,
    u64* s_key, float* s_cx, float* s_cy, float* s_cz, float (*s_win)[3])
{
#pragma clang fp contract(off)
  u64 ck[16]; float cx[16], cy[16], cz[16];
#pragma unroll
  for (int i = 0; i < 16; ++i) {
    int idx = tid + i * 256;
    bool v = idx < m;
    u64 k = v ? s_pool[idx] : 0ull;
    int gi = v ? (int)(0x1FFFFu - (u32)(k & 0x1FFFFull)) : 0;
    float4 c = bpts[gi];
    ck[i] = k; cx[i] = c.y; cy[i] = c.z; cz[i] = c.w;
  }
  int j = 0;
  for (int t = 0; t < jmax; ++t) {
    u64 tk = ck[0]; float mx = cx[0], my = cy[0], mz = cz[0];
#pragma unroll
    for (int i = 1; i < 16; ++i)
      if (ck[i] > tk) { tk = ck[i]; mx = cx[i]; my = cy[i]; mz = cz[i]; }
    BMax w = block_max(tk, mx, my, mz, lane, wv, sb, s_key, s_cx, s_cy, s_cz);
    sb ^= 4;
    if (w.k <= cutk) break;
    if (tid == 0) { s_win[t][0]=w.x; s_win[t][1]=w.y; s_win[t][2]=w.z; }
    j = t + 1;
#pragma unroll
    for (int i = 0; i < 16; ++i) {
      float dx = cx[i]-w.x, dy = cy[i]-w.y, dz = cz[i]-w.z;
      float d2 = __fadd_rn(__fadd_rn(__fmul_rn(dx,dx), __fmul_rn(dy,dy)),
                           __fmul_rn(dz,dz));
      float nd = fminf(__uint_as_float((u32)(ck[i] >> 32)), d2);
      ck[i] = ((u64)__float_as_uint(nd) << 32) | (ck[i] & 0xFFFFFFFFull);
    }
  }
  __syncthreads();                           // s_win visible
  return j;
}

#define CE(a,b) { if (sk[a] < sk[b]) { u64 t_ = sk[a]; sk[a] = sk[b]; sk[b] = t_; } }

__global__ __launch_bounds__(TPB, 1)
void fps_kernel(const float4* __restrict__ pts, float* __restrict__ out,
                u32* __restrict__ slots)
{
#pragma clang fp contract(off)
  const int batch = blockIdx.x >> 5;
  const int rank  = blockIdx.x & (NB - 1);
  const int tid   = threadIdx.x;
  const int lane  = tid & 63;
  const int wv    = tid >> 6;
  const int ws_id = rank * 4 + wv;           // wave-slot 0..127

  __shared__ u64   s_pool[NCAND];            // 32 KB
  __shared__ u64   s_cutq[4];
  __shared__ float s_win[JCAP][3];
  __shared__ u64   s_key[8];
  __shared__ float s_cx[8], s_cy[8], s_cz[8];
  __shared__ int   s_cnt2[2];

  const float4* bpts = pts + (size_t)batch * NPB;
  u32* bslots = slots + (size_t)batch * (RING * RBU32);
  const int base = rank * (TPB * PPT);

  float px[PPT], py[PPT], pz[PPT], dist[PPT];
  float4 seed = bpts[0];
  const float sx = seed.y, sy = seed.z, sz = seed.w;
#pragma unroll
  for (int k = 0; k < PPT; ++k) {
    float4 p = bpts[base + k * TPB + tid];   // row = (b, x, y, z)
    px[k] = p.y; py[k] = p.z; pz[k] = p.w;
    float dx = px[k]-sx, dy = py[k]-sy, dz = pz[k]-sz;
    dist[k] = __fadd_rn(__fadd_rn(__fmul_rn(dx,dx), __fmul_rn(dy,dy)),
                        __fmul_rn(dz,dz));   // == reference dist init
  }
  if (rank == 0 && tid == 0) {
    float4 o; o.x=(float)batch; o.y=sx; o.z=sy; o.w=sz;
    *(float4*)(out + (size_t)batch * MSAMP * 4) = o;
  }
  if (tid == 0) { s_cnt2[0] = 0; s_cnt2[1] = 0; }
  __syncthreads();

  int S = 0; u32 r = 0; int sb = 0;
  float ox = 0.f, oy = 0.f, oz = 0.f;

  while (S < MSAMP - 1) {
    r += 1;
    const int rem = (MSAMP - 1) - S;
    const int jmax = (rem < JCAP) ? rem : JCAP;

    // ---- EXTRACT (EXACT dists): sort-16 + 32 tournament pops ----
    u64 sk[16];
#pragma unroll
    for (int k = 0; k < PPT; ++k)
      sk[k] = ((u64)__float_as_uint(dist[k]) << 32) | ((u64)r << 17) |
              (u64)(0x1FFFFu - (u32)(base + k * TPB + tid));
    // Batcher odd-even mergesort, 16 elems, descending (63 CEs)
    CE(0,1) CE(2,3) CE(4,5) CE(6,7) CE(8,9) CE(10,11) CE(12,13) CE(14,15)
    CE(0,2) CE(1,3) CE(4,6) CE(5,7) CE(8,10) CE(9,11) CE(12,14) CE(13,15)
    CE(1,2) CE(5,6) CE(9,10) CE(13,14)
    CE(0,4) CE(1,5) CE(2,6) CE(3,7) CE(8,12) CE(9,13) CE(10,14) CE(11,15)
    CE(2,4) CE(3,5) CE(10,12) CE(11,13)
    CE(1,2) CE(3,4) CE(5,6) CE(9,10) CE(11,12) CE(13,14)
    CE(0,8) CE(1,9) CE(2,10) CE(3,11) CE(4,12) CE(5,13) CE(6,14) CE(7,15)
    CE(4,8) CE(5,9) CE(6,10) CE(7,11)
    CE(2,4) CE(3,5) CE(6,8) CE(7,9) CE(10,12) CE(11,13)
    CE(1,2) CE(3,4) CE(5,6) CE(7,8) CE(9,10) CE(11,12) CE(13,14)

    u32x4 shipq; shipq.x = shipq.y = shipq.z = shipq.w = 0u;
#pragma unroll
    for (int c = 0; c < KW; ++c) {           // 32 pops, O(1) each
      u64 wk = bcast_key(dpp_max64_to63(sk[0]), 63);
      if (sk[0] == wk) {                     // unique winner shifts list
#pragma unroll
        for (int i = 0; i < 15; ++i) sk[i] = sk[i+1];
        sk[15] = 0ull;
      }
      u32 lo = (u32)(wk & 0xFFFFFFFFull), hi = (u32)(wk >> 32);
      if (lane == (c >> 1)) {
        if (c & 1) { shipq.z = lo; shipq.w = hi; }
        else       { shipq.x = lo; shipq.y = hi; }
      }
    }

    // ---- SHIP: lanes 0..15 store one dwordx4 (2 cands), unacked ----
    u32* ring = bslots + (size_t)(r & 1u) * RBU32;
    if (lane < 16) st16_sys(ring + (ws_id * KW + lane * 2) * 2, shipq);
    if (tid == 0) s_cnt2[(r + 1) & 1] = 0;   // overlap flight: reset next ctr

    // ---- POLL: wave's 1024-cand quarter, 8 batched loads/lane ----
    const int cb = wv * 1024 + lane * 2;
    const u32 *P0 = ring + (cb      ) * 2, *P1 = ring + (cb + 128) * 2,
              *P2 = ring + (cb + 256) * 2, *P3 = ring + (cb + 384) * 2,
              *P4 = ring + (cb + 512) * 2, *P5 = ring + (cb + 640) * 2,
              *P6 = ring + (cb + 768) * 2, *P7 = ring + (cb + 896) * 2;
    u32x4 q0,q1,q2,q3,q4,q5,q6,q7;
    for (u32 it = 0; ; ++it) {
      ld16x8_sys(P0,P1,P2,P3,P4,P5,P6,P7, q0,q1,q2,q3,q4,q5,q6,q7);
      bool ok = ((q0.x>>17)==r)&&((q0.z>>17)==r)&&((q1.x>>17)==r)&&((q1.z>>17)==r)&&
                ((q2.x>>17)==r)&&((q2.z>>17)==r)&&((q3.x>>17)==r)&&((q3.z>>17)==r)&&
                ((q4.x>>17)==r)&&((q4.z>>17)==r)&&((q5.x>>17)==r)&&((q5.z>>17)==r)&&
                ((q6.x>>17)==r)&&((q6.z>>17)==r)&&((q7.x>>17)==r)&&((q7.z>>17)==r);
      if (__ballot(ok) == ~0ull) break;
      if (it >= 1) __builtin_amdgcn_s_sleep(1);
    }

    u64 kk[16] = { ((u64)q0.y<<32)|q0.x, ((u64)q0.w<<32)|q0.z,
                   ((u64)q1.y<<32)|q1.x, ((u64)q1.w<<32)|q1.z,
                   ((u64)q2.y<<32)|q2.x, ((u64)q2.w<<32)|q2.z,
                   ((u64)q3.y<<32)|q3.x, ((u64)q3.w<<32)|q3.z,
                   ((u64)q4.y<<32)|q4.x, ((u64)q4.w<<32)|q4.z,
                   ((u64)q5.y<<32)|q5.x, ((u64)q5.w<<32)|q5.z,
                   ((u64)q6.y<<32)|q6.x, ((u64)q6.w<<32)|q6.z,
                   ((u64)q7.y<<32)|q7.x, ((u64)q7.w<<32)|q7.z };

    // ---- CUTOFF: lanes L&15==15 hold cand-31 of 8 wave-slots (odd half)
    u64 cm = 0ull;
    if ((lane & 15) == 15) {
      cm = kk[1];
      if (kk[3]  > cm) cm = kk[3];  if (kk[5]  > cm) cm = kk[5];
      if (kk[7]  > cm) cm = kk[7];  if (kk[9]  > cm) cm = kk[9];
      if (kk[11] > cm) cm = kk[11]; if (kk[13] > cm) cm = kk[13];
      if (kk[15] > cm) cm = kk[15];
    }
    u64 qc = bcast_key(dpp_max64_to63(cm), 63);
    if (lane == 0) s_cutq[wv] = qc;
    __syncthreads();                         // barrier A
    u64 cutk = s_cutq[0];
    if (s_cutq[1] > cutk) cutk = s_cutq[1];
    if (s_cutq[2] > cutk) cutk = s_cutq[2];
    if (s_cutq[3] > cutk) cutk = s_cutq[3];

    // ---- PRUNE from poll regs (wave-aggregated LDS append) ----
    bool hh[16]; int myoff[16]; int tot = 0;
    const u64 ltmask = (1ull << lane) - 1ull;
#pragma unroll
    for (int i = 0; i < 16; ++i) {
      hh[i] = kk[i] > cutk;
      u64 b = __ballot(hh[i]);
      myoff[i] = tot + __popcll(b & ltmask);
      tot += __popcll(b);
    }
    int pbase = 0;
    if (lane == 0) pbase = atomicAdd(&s_cnt2[r & 1], tot);
    pbase = __builtin_amdgcn_readfirstlane(pbase);
#pragma unroll
    for (int i = 0; i < 16; ++i)
      if (hh[i]) s_pool[pbase + myoff[i]] = kk[i];
    __syncthreads();                         // barrier B
    const int m = s_cnt2[r & 1];

    // ---- SIM (tiered; exact pool) ----
    int j;
    if (m <= 256)
      j = sim_wave<4>(s_pool, m, cutk, jmax, lane, bpts, ox, oy, oz);
    else if (m <= 512)
      j = sim_wave<8>(s_pool, m, cutk, jmax, lane, bpts, ox, oy, oz);
    else if (m <= 1024)
      j = sim_wave<16>(s_pool, m, cutk, jmax, lane, bpts, ox, oy, oz);
    else {
      j = sim_block(s_pool, m, cutk, jmax, tid, lane, wv, sb, bpts,
                    s_key, s_cx, s_cy, s_cz, s_win);
      if (lane < j) { ox = s_win[lane][0]; oy = s_win[lane][1]; oz = s_win[lane][2]; }
    }

    // ---- COMMIT rows + exact register dist update (ascending order) ----
    if (rank == 0 && wv == 0 && lane < j) {
      float4 o; o.x = (float)batch; o.y = ox; o.z = oy; o.w = oz;
      *(float4*)(out + (size_t)(batch * MSAMP + S + 1 + lane) * 4) = o;
    }
    for (int i = 0; i < j; ++i) {
      float wx = bcast_f32(ox, i), wy = bcast_f32(oy, i), wz = bcast_f32(oz, i);
#pragma unroll
      for (int k = 0; k < PPT; ++k) {
        float dx = px[k]-wx, dy = py[k]-wy, dz = pz[k]-wz;
        float d2 = __fadd_rn(__fadd_rn(__fmul_rn(dx,dx), __fmul_rn(dy,dy)),
                             __fmul_rn(dz,dz));
        dist[k] = fminf(dist[k], d2);
      }
    }
    S += j;
  }
}

extern "C" void kernel_launch(void* const* d_in, const int* in_sizes, int n_in,
                              void* d_out, int out_size, void* d_ws, size_t ws_size,
                              hipStream_t stream) {
  const float4* pts = (const float4*)d_in[0];
  float* out = (float*)d_out;
  u32* slots = (u32*)d_ws;

  // Zero both batches' rings (128 KB): stale tags can never validate.
  hipMemsetAsync(d_ws, 0, (size_t)2 * RING * RBU32 * 4, stream);

  dim3 grid(2 * NB), block(TPB);
  hipLaunchKernelGGL(fps_kernel, grid, block, 0, stream, pts, out, slots);
}

// Round 10
// 4910.790 us; speedup vs baseline: 1.3547x; 1.3547x over previous
//
#include <hip/hip_runtime.h>

// FPS: 2 batches x 131072 pts, 4096 samples/batch, seed = point 0.
// EXACT certified lookahead FPS, v5: KW=16, exact extraction, and a
// BARRIER-FREE wave-register sim for ALL pool sizes (NC up to 32).
//
// Evidence r0-r9:
//  * sys-scope rendezvous RT ~2.5us is the floor (sc0 never resolves
//    cross-CU on this part, r0-r4). Lookahead amortizes it (r6: 3667us
//    @ KW=8). r8 (KW=16, stale extraction) = 5396: stale cutoff halves
//    depth. r9 (KW=32, exact) = 6652: depth fine but m ~ 2000 > 1024
//    forced the sim_block tier (a __syncthreads + LDS trip PER SIM STEP
//    + 4096 scattered gathers) ~ 7us/round of sim => regression.
//  * Fix: KW=16 caps m at 128*15 = 1920; with __launch_bounds__(256,1)
//    a wave can hold NC=32 (2048-cand) pools in registers => the
//    barrier-free wave sim covers the worst case; sim_block deleted.
//
// Per rendezvous round r (all 32 blocks of a batch):
//  1. EXTRACT (exact dists): per-lane Batcher-16 sort (63 CEs, compile-
//     time indices -> registers) + 16 DPP-tournament pops (O(1) each;
//     winner lane shifts its sorted list). Pop c -> ship quad of lane
//     c>>1 (half c&1); cand 15 of each wave == its 16th-best.
//     Key = dist_bits<<32 | r<<17 | (0x1FFFF - idx): u64 order ==
//     (dist desc, idx asc) == jnp.argmax first-index tiebreak.
//  2. SHIP: lanes 0..7 store one dwordx4 (2 cands), sys scope, unacked.
//     POLL: 4 batched dwordx4/lane (ONE vmcnt RT) covers the wave's
//     512-cand quarter; s_sleep backoff after the first retry.
//     (Layout verbatim from r8, which passed refcheck.)
//  3. CUTOFF = max over 128 wave-slots of 16th-best key, read straight
//     from poll regs (lanes L&7==7 hold cand-15s in odd kk entries).
//     Exact keys => any unshipped point key < its wave's 16th <= cutk.
//  4. PRUNE: keys > cutk -> wave-aggregated LDS append (pool SET is
//     block-identical; order irrelevant: winners found by u64 max).
//     m <= 1920 guaranteed.
//  5. SIM (no barriers): wave-register tier NC=8/16/24/32 by m; coords
//     gathered from L2-resident pts[idx] (2MB/batch fits an XCD L2).
//     Certified loop, FULL-KEY test wk > cutk every step; t=0 is
//     guaranteed (global max = some wave's exact top-1, in pool, and
//     strictly > cutk by key uniqueness) => j >= 1, no livelock.
//  6. COMMIT: rank0 wave0 writes rows S+1..S+j; ALL blocks min-update
//     their 4096 register dists per winner in ascending order (exact
//     reference fp sequence => bit-exact).
//
// Ring safety (RING=2): a wave ships round r+1 (overwriting slot r-1)
// only after its poll(r) passed, which requires ALL 128 waves stored r,
// each after its poll(r-1) finished reading slot r-1. Tags: bits 17-31
// of each cand's lo word == r; zeroed/stale slots never match (1 <= r
// <= 4095 < 2^15 since j >= 1 every round).

#define NB    32
#define TPB   256
#define PPT   16
#define NPB   131072
#define MSAMP 4096
#define RING  2
#define KW    16
#define NWAVE 128
#define NCAND (NWAVE * KW)      // 2048 candidates / round / batch
#define RBU32 (NCAND * 2)       // 4096 u32 = 16KB per ring slot
#define JCAP  64

typedef unsigned long long u64;
typedef unsigned int u32;
typedef __attribute__((ext_vector_type(4))) u32 u32x4;

__device__ __forceinline__ void st16_sys(u32* p, u32x4 v) {
  asm volatile("global_store_dwordx4 %0, %1, off sc0 sc1"
               :: "v"(p), "v"(v) : "memory");
}
// 4 poll loads issued back-to-back, ONE vmcnt drain (single RT).
__device__ __forceinline__ void ld16x4_sys(
    const u32* p0, const u32* p1, const u32* p2, const u32* p3,
    u32x4& q0, u32x4& q1, u32x4& q2, u32x4& q3) {
  asm volatile(
    "global_load_dwordx4 %0, %4, off sc0 sc1\n\t"
    "global_load_dwordx4 %1, %5, off sc0 sc1\n\t"
    "global_load_dwordx4 %2, %6, off sc0 sc1\n\t"
    "global_load_dwordx4 %3, %7, off sc0 sc1\n\t"
    "s_waitcnt vmcnt(0)"
    : "=v"(q0), "=v"(q1), "=v"(q2), "=v"(q3)
    : "v"(p0), "v"(p1), "v"(p2), "v"(p3)
    : "memory");
}

// ---- DPP helpers (proven r2-r9) ---------------------------------------
template<int CTRL>
__device__ __forceinline__ u64 dpp_move64(u64 x) {
  int lo = (int)(u32)(x & 0xFFFFFFFFull);
  int hi = (int)(u32)(x >> 32);
  int nlo = __builtin_amdgcn_update_dpp(lo, lo, CTRL, 0xF, 0xF, false);
  int nhi = __builtin_amdgcn_update_dpp(hi, hi, CTRL, 0xF, 0xF, false);
  return ((u64)(u32)nhi << 32) | (u64)(u32)nlo;
}
#define DPP_ROW_SHR(n)  (0x110 + (n))
#define DPP_BCAST15     0x142
#define DPP_BCAST31     0x143

__device__ __forceinline__ u64 dpp_max64_to63(u64 k) {
  u64 t;
  t = dpp_move64<DPP_ROW_SHR(1)>(k); if (t > k) k = t;
  t = dpp_move64<DPP_ROW_SHR(2)>(k); if (t > k) k = t;
  t = dpp_move64<DPP_ROW_SHR(4)>(k); if (t > k) k = t;
  t = dpp_move64<DPP_ROW_SHR(8)>(k); if (t > k) k = t;
  t = dpp_move64<DPP_BCAST15>(k);    if (t > k) k = t;
  t = dpp_move64<DPP_BCAST31>(k);    if (t > k) k = t;
  return k;                                   // lane63 = wave max
}
__device__ __forceinline__ u64 bcast_key(u64 k, int srclane) {
  u32 lo = (u32)__builtin_amdgcn_readlane((int)(u32)(k & 0xFFFFFFFFull), srclane);
  u32 hi = (u32)__builtin_amdgcn_readlane((int)(u32)(k >> 32), srclane);
  return ((u64)hi << 32) | (u64)lo;
}
__device__ __forceinline__ float bcast_f32(float v, int srclane) {
  return __uint_as_float((u32)__builtin_amdgcn_readlane((int)__float_as_uint(v), srclane));
}

// ---- wave-register sim (exact pool; full-key certified; NO barriers) --
template<int NC>
__device__ __forceinline__ int sim_wave(const u64* s_pool, int m, u64 cutk,
    int jmax, int lane, const float4* bpts,
    float& ox, float& oy, float& oz)
{
#pragma clang fp contract(off)
  u64 ck[NC]; float cx[NC], cy[NC], cz[NC];
#pragma unroll
  for (int i = 0; i < NC; ++i) {
    int idx = lane + i * 64;
    bool v = idx < m;
    u64 k = v ? s_pool[idx] : 0ull;
    int gi = v ? (int)(0x1FFFFu - (u32)(k & 0x1FFFFull)) : 0;
    float4 c = bpts[gi];
    ck[i] = k; cx[i] = c.y; cy[i] = c.z; cz[i] = c.w;
  }
  int j = 0;
  for (int t = 0; t < jmax; ++t) {
    u64 tk = ck[0]; float mx = cx[0], my = cy[0], mz = cz[0];
#pragma unroll
    for (int i = 1; i < NC; ++i)
      if (ck[i] > tk) { tk = ck[i]; mx = cx[i]; my = cy[i]; mz = cz[i]; }
    u64 wk = bcast_key(dpp_max64_to63(tk), 63);
    if (wk <= cutk) break;                   // full-key cert (t=0 never fails)
    int wl = __ffsll(__ballot(tk == wk)) - 1;
    float wx = bcast_f32(mx, wl), wy = bcast_f32(my, wl), wz = bcast_f32(mz, wl);
    if (lane == t) { ox = wx; oy = wy; oz = wz; }
    j = t + 1;
#pragma unroll
    for (int i = 0; i < NC; ++i) {
      float dx = cx[i]-wx, dy = cy[i]-wy, dz = cz[i]-wz;
      float d2 = __fadd_rn(__fadd_rn(__fmul_rn(dx,dx), __fmul_rn(dy,dy)),
                           __fmul_rn(dz,dz));
      float nd = fminf(__uint_as_float((u32)(ck[i] >> 32)), d2);
      ck[i] = ((u64)__float_as_uint(nd) << 32) | (ck[i] & 0xFFFFFFFFull);
    }
  }
  return j;
}

#define CE(a,b) { if (sk[a] < sk[b]) { u64 t_ = sk[a]; sk[a] = sk[b]; sk[b] = t_; } }

__global__ __launch_bounds__(TPB, 1)
void fps_kernel(const float4* __restrict__ pts, float* __restrict__ out,
                u32* __restrict__ slots)
{
#pragma clang fp contract(off)
  const int batch = blockIdx.x >> 5;
  const int rank  = blockIdx.x & (NB - 1);
  const int tid   = threadIdx.x;
  const int lane  = tid & 63;
  const int wv    = tid >> 6;
  const int ws_id = rank * 4 + wv;           // wave-slot 0..127

  __shared__ u64   s_pool[NCAND];            // 16 KB
  __shared__ u64   s_cutq[4];
  __shared__ int   s_cnt2[2];

  const float4* bpts = pts + (size_t)batch * NPB;
  u32* bslots = slots + (size_t)batch * (RING * RBU32);
  const int base = rank * (TPB * PPT);

  float px[PPT], py[PPT], pz[PPT], dist[PPT];
  float4 seed = bpts[0];
  const float sx = seed.y, sy = seed.z, sz = seed.w;
#pragma unroll
  for (int k = 0; k < PPT; ++k) {
    float4 p = bpts[base + k * TPB + tid];   // row = (b, x, y, z)
    px[k] = p.y; py[k] = p.z; pz[k] = p.w;
    float dx = px[k]-sx, dy = py[k]-sy, dz = pz[k]-sz;
    dist[k] = __fadd_rn(__fadd_rn(__fmul_rn(dx,dx), __fmul_rn(dy,dy)),
                        __fmul_rn(dz,dz));   // == reference dist init
  }
  if (rank == 0 && tid == 0) {
    float4 o; o.x=(float)batch; o.y=sx; o.z=sy; o.w=sz;
    *(float4*)(out + (size_t)batch * MSAMP * 4) = o;
  }
  if (tid == 0) { s_cnt2[0] = 0; s_cnt2[1] = 0; }
  __syncthreads();

  int S = 0; u32 r = 0;
  float ox = 0.f, oy = 0.f, oz = 0.f;

  while (S < MSAMP - 1) {
    r += 1;
    const int rem = (MSAMP - 1) - S;
    const int jmax = (rem < JCAP) ? rem : JCAP;

    // ---- EXTRACT (EXACT dists): sort-16 + 16 tournament pops ----
    u64 sk[16];
#pragma unroll
    for (int k = 0; k < PPT; ++k)
      sk[k] = ((u64)__float_as_uint(dist[k]) << 32) | ((u64)r << 17) |
              (u64)(0x1FFFFu - (u32)(base + k * TPB + tid));
    // Batcher odd-even mergesort, 16 elems, descending (63 CEs)
    CE(0,1) CE(2,3) CE(4,5) CE(6,7) CE(8,9) CE(10,11) CE(12,13) CE(14,15)
    CE(0,2) CE(1,3) CE(4,6) CE(5,7) CE(8,10) CE(9,11) CE(12,14) CE(13,15)
    CE(1,2) CE(5,6) CE(9,10) CE(13,14)
    CE(0,4) CE(1,5) CE(2,6) CE(3,7) CE(8,12) CE(9,13) CE(10,14) CE(11,15)
    CE(2,4) CE(3,5) CE(10,12) CE(11,13)
    CE(1,2) CE(3,4) CE(5,6) CE(9,10) CE(11,12) CE(13,14)
    CE(0,8) CE(1,9) CE(2,10) CE(3,11) CE(4,12) CE(5,13) CE(6,14) CE(7,15)
    CE(4,8) CE(5,9) CE(6,10) CE(7,11)
    CE(2,4) CE(3,5) CE(6,8) CE(7,9) CE(10,12) CE(11,13)
    CE(1,2) CE(3,4) CE(5,6) CE(7,8) CE(9,10) CE(11,12) CE(13,14)

    u32x4 shipq; shipq.x = shipq.y = shipq.z = shipq.w = 0u;
#pragma unroll
    for (int c = 0; c < KW; ++c) {           // 16 pops, O(1) each
      u64 wk = bcast_key(dpp_max64_to63(sk[0]), 63);
      if (sk[0] == wk) {                     // unique winner shifts list
#pragma unroll
        for (int i = 0; i < 15; ++i) sk[i] = sk[i+1];
        sk[15] = 0ull;
      }
      u32 lo = (u32)(wk & 0xFFFFFFFFull), hi = (u32)(wk >> 32);
      if (lane == (c >> 1)) {
        if (c & 1) { shipq.z = lo; shipq.w = hi; }
        else       { shipq.x = lo; shipq.y = hi; }
      }
    }

    // ---- SHIP: lanes 0..7 store one dwordx4 (2 cands each), unacked ----
    u32* ring = bslots + (size_t)(r & 1u) * RBU32;
    if (lane < 8) st16_sys(ring + (ws_id * 16 + lane * 2) * 2, shipq);
    if (tid == 0) s_cnt2[(r + 1) & 1] = 0;   // overlap flight: reset next ctr

    // ---- POLL: wave's 512-cand quarter, 4 batched loads/lane ----
    const int cb = wv * 512 + lane * 2;
    const u32 *P0 = ring + (cb      ) * 2, *P1 = ring + (cb + 128) * 2,
              *P2 = ring + (cb + 256) * 2, *P3 = ring + (cb + 384) * 2;
    u32x4 q0, q1, q2, q3;
    for (u32 it = 0; ; ++it) {
      ld16x4_sys(P0, P1, P2, P3, q0, q1, q2, q3);
      bool ok = ((q0.x>>17)==r) && ((q0.z>>17)==r) && ((q1.x>>17)==r) &&
                ((q1.z>>17)==r) && ((q2.x>>17)==r) && ((q2.z>>17)==r) &&
                ((q3.x>>17)==r) && ((q3.z>>17)==r);
      if (__ballot(ok) == ~0ull) break;
      if (it >= 1) __builtin_amdgcn_s_sleep(1);
    }

    u64 kk[8] = { ((u64)q0.y<<32)|q0.x, ((u64)q0.w<<32)|q0.z,
                  ((u64)q1.y<<32)|q1.x, ((u64)q1.w<<32)|q1.z,
                  ((u64)q2.y<<32)|q2.x, ((u64)q2.w<<32)|q2.z,
                  ((u64)q3.y<<32)|q3.x, ((u64)q3.w<<32)|q3.z };

    // ---- CUTOFF: lanes L&7==7 hold cand-15 of 4 wave-slots (odd half) ----
    u64 cm = 0ull;
    if ((lane & 7) == 7) {
      cm = kk[1];
      if (kk[3] > cm) cm = kk[3];
      if (kk[5] > cm) cm = kk[5];
      if (kk[7] > cm) cm = kk[7];
    }
    u64 qc = bcast_key(dpp_max64_to63(cm), 63);
    if (lane == 0) s_cutq[wv] = qc;
    __syncthreads();                         // barrier A
    u64 cutk = s_cutq[0];
    if (s_cutq[1] > cutk) cutk = s_cutq[1];
    if (s_cutq[2] > cutk) cutk = s_cutq[2];
    if (s_cutq[3] > cutk) cutk = s_cutq[3];

    // ---- PRUNE from poll regs (wave-aggregated LDS append) ----
    bool hh[8]; int myoff[8]; int tot = 0;
    const u64 ltmask = (1ull << lane) - 1ull;
#pragma unroll
    for (int i = 0; i < 8; ++i) {
      hh[i] = kk[i] > cutk;
      u64 b = __ballot(hh[i]);
      myoff[i] = tot + __popcll(b & ltmask);
      tot += __popcll(b);
    }
    int pbase = 0;
    if (lane == 0) pbase = atomicAdd(&s_cnt2[r & 1], tot);
    pbase = __builtin_amdgcn_readfirstlane(pbase);
#pragma unroll
    for (int i = 0; i < 8; ++i)
      if (hh[i]) s_pool[pbase + myoff[i]] = kk[i];
    __syncthreads();                         // barrier B
    const int m = s_cnt2[r & 1];             // m <= 128*15 = 1920

    // ---- SIM (wave-register tiers only; no barriers) ----
    int j;
    if (m <= 512)
      j = sim_wave<8>(s_pool, m, cutk, jmax, lane, bpts, ox, oy, oz);
    else if (m <= 1024)
      j = sim_wave<16>(s_pool, m, cutk, jmax, lane, bpts, ox, oy, oz);
    else if (m <= 1536)
      j = sim_wave<24>(s_pool, m, cutk, jmax, lane, bpts, ox, oy, oz);
    else
      j = sim_wave<32>(s_pool, m, cutk, jmax, lane, bpts, ox, oy, oz);

    // ---- COMMIT rows + exact register dist update (ascending order) ----
    if (rank == 0 && wv == 0 && lane < j) {
      float4 o; o.x = (float)batch; o.y = ox; o.z = oy; o.w = oz;
      *(float4*)(out + (size_t)(batch * MSAMP + S + 1 + lane) * 4) = o;
    }
    for (int i = 0; i < j; ++i) {
      float wx = bcast_f32(ox, i), wy = bcast_f32(oy, i), wz = bcast_f32(oz, i);
#pragma unroll
      for (int k = 0; k < PPT; ++k) {
        float dx = px[k]-wx, dy = py[k]-wy, dz = pz[k]-wz;
        float d2 = __fadd_rn(__fadd_rn(__fmul_rn(dx,dx), __fmul_rn(dy,dy)),
                             __fmul_rn(dz,dz));
        dist[k] = fminf(dist[k], d2);
      }
    }
    S += j;
  }
}

extern "C" void kernel_launch(void* const* d_in, const int* in_sizes, int n_in,
                              void* d_out, int out_size, void* d_ws, size_t ws_size,
                              hipStream_t stream) {
  const float4* pts = (const float4*)d_in[0];
  float* out = (float*)d_out;
  u32* slots = (u32*)d_ws;

  // Zero both batches' rings (64 KB): stale tags can never validate.
  hipMemsetAsync(d_ws, 0, (size_t)2 * RING * RBU32 * 4, stream);

  dim3 grid(2 * NB), block(TPB);
  hipLaunchKernelGGL(fps_kernel, grid, block, 0, stream, pts, out, slots);
}

// Round 12
// 3613.329 us; speedup vs baseline: 1.8411x; 1.3591x over previous
//
#include <hip/hip_runtime.h>

// FPS: 2 batches x 131072 pts, 4096 samples/batch, seed = point 0.
// EXACT certified lookahead FPS, v7 = r6 (3667us, PASSED) + two
// surgical, individually-proven changes:
//  (A) sim_wave<14> tier: pool bound m <= 896 is PROVABLE (cutk = max
//      over 128 wave-slots of rank-7 key => only ranks 0..6 pass the
//      strict > cutk prune => m <= 7*128). r6's tiers stopped at 512 and
//      fell into sim_block (a __syncthreads + LDS block_max PER SIM
//      STEP) for m in (513,896]. NC=14 covers 896 exactly; sim_block
//      deleted (dead code).
//  (B) wave-aggregated prune (ballot offsets + ONE LDS atomic per wave,
//      the r9/r10-proven pattern) replacing r6's per-candidate atomicAdd
//      (~m serialized LDS atomics per round).
// ALL other code paths are r6 VERBATIM (extraction with winner rescans,
// ship layout, batched all-sys poll, LDS mirror, per-wave DPP cutoff,
// dist-cert sim, commit) - r11's rewritten plumbing failed (absmax 157)
// and is abandoned.
//
// Evidence r0-r10: sys-scope rendezvous RT ~2.5us is the floor (sc0
// never resolves cross-CU on this part, r0-r4). Certified lookahead
// amortizes it: r6 = 3667us @ KW=8, j~8 (best). r8 stale extraction
// halves depth (5396); r9 KW=32 forces block-tier sim (6652); r10
// key-only cands pay a pts[] gather per sim (4911). => KW=8 + coords
// travel with candidates + register-only sim.
//
// Per rendezvous round r (all 32 blocks of a batch):
//  1. EXTRACT per wave (exact dists, no barriers): 8 DPP-tournament
//     pops + winner-lane rescan with removal mask. Lanes 2c/2c+1
//     capture pop-c into ship quads {keylo,keyhi,x,y} / {r,z,0,0}.
//     Key = dist_bits<<32 | r<<17 | (0x1FFFF - idx): u64 order ==
//     (dist desc, idx asc) == jnp.argmax first-index tiebreak.
//  2. SHIP: lanes 0..15 store 16B each, sys scope, unacked.
//  3. POLL: wave's 512-quad quarter, 8 batched loads/lane (ONE vmcnt
//     RT), all-sys; mirror to LDS (68-u32 padded slots); barrier.
//  4. CUTOFF = max over 128 wave-slots of 8th-best key (per-wave DPP
//     over the mirror, no barrier).
//  5. PRUNE: keys > cutk -> 5-u32 LDS pool (change B); barrier.
//  6. SIM: wave-register tiers NC=1/2/4/8/14 (change A), no barriers;
//     t=0 always commits (global max = someone's exact top-1, in pool);
//     t>=1 iff winner dist STRICTLY > cutoff dist. j >= 1 always.
//  7. COMMIT: rank0 wave0 writes rows S+1..S+j; all blocks min-update
//     register dists per winner, ascending (reference fp order =>
//     bit-exact).
//
// Ring safety (RING=2): a wave ships round r+1 (overwriting slot r-1)
// only after its block's mirror barrier of round r, which requires all
// 4 waves' quarter-polls of r, which require ALL 128 wave-slots stored
// r, each after that wave's poll(r-1) finished reading slot r-1. Tags
// embed r; zeroed/stale slots never match (1 <= r <= 4095 < 2^15).

#define NB    32
#define TPB   256
#define PPT   16
#define NPB   131072
#define MSAMP 4096
#define RING  2
#define KW    8                 // candidates per wave
#define NWAVE 128               // waves per batch
#define NQUAD (NWAVE * 16)      // 2048 quads per round per batch
#define RB_U32 (NQUAD * 4)      // 8192 u32 = 32KB per ring slot
#define NCAND (NWAVE * KW)      // 1024
#define JCAP  64

typedef unsigned long long u64;
typedef unsigned int u32;
typedef __attribute__((ext_vector_type(4))) u32 u32x4;

__device__ __forceinline__ void st16_sys(u32* p, u32x4 v) {
  asm volatile("global_store_dwordx4 %0, %1, off sc0 sc1"
               :: "v"(p), "v"(v) : "memory");
}
// 8 poll loads issued back-to-back, ONE vmcnt drain (single RT).
__device__ __forceinline__ void ld16x8_sys(
    const u32* p0, const u32* p1, const u32* p2, const u32* p3,
    const u32* p4, const u32* p5, const u32* p6, const u32* p7,
    u32x4& q0, u32x4& q1, u32x4& q2, u32x4& q3,
    u32x4& q4, u32x4& q5, u32x4& q6, u32x4& q7) {
  asm volatile(
    "global_load_dwordx4 %0, %8, off sc0 sc1\n\t"
    "global_load_dwordx4 %1, %9, off sc0 sc1\n\t"
    "global_load_dwordx4 %2, %10, off sc0 sc1\n\t"
    "global_load_dwordx4 %3, %11, off sc0 sc1\n\t"
    "global_load_dwordx4 %4, %12, off sc0 sc1\n\t"
    "global_load_dwordx4 %5, %13, off sc0 sc1\n\t"
    "global_load_dwordx4 %6, %14, off sc0 sc1\n\t"
    "global_load_dwordx4 %7, %15, off sc0 sc1\n\t"
    "s_waitcnt vmcnt(0)"
    : "=v"(q0), "=v"(q1), "=v"(q2), "=v"(q3),
      "=v"(q4), "=v"(q5), "=v"(q6), "=v"(q7)
    : "v"(p0), "v"(p1), "v"(p2), "v"(p3),
      "v"(p4), "v"(p5), "v"(p6), "v"(p7)
    : "memory");
}

// ---- DPP helpers (proven r2-r10) ---------------------------------------
template<int CTRL>
__device__ __forceinline__ u64 dpp_move64(u64 x) {
  int lo = (int)(u32)(x & 0xFFFFFFFFull);
  int hi = (int)(u32)(x >> 32);
  int nlo = __builtin_amdgcn_update_dpp(lo, lo, CTRL, 0xF, 0xF, false);
  int nhi = __builtin_amdgcn_update_dpp(hi, hi, CTRL, 0xF, 0xF, false);
  return ((u64)(u32)nhi << 32) | (u64)(u32)nlo;
}
#define DPP_ROW_SHR(n)  (0x110 + (n))
#define DPP_BCAST15     0x142
#define DPP_BCAST31     0x143

__device__ __forceinline__ u64 dpp_max64_to63(u64 k) {
  u64 t;
  t = dpp_move64<DPP_ROW_SHR(1)>(k); if (t > k) k = t;
  t = dpp_move64<DPP_ROW_SHR(2)>(k); if (t > k) k = t;
  t = dpp_move64<DPP_ROW_SHR(4)>(k); if (t > k) k = t;
  t = dpp_move64<DPP_ROW_SHR(8)>(k); if (t > k) k = t;
  t = dpp_move64<DPP_BCAST15>(k);    if (t > k) k = t;
  t = dpp_move64<DPP_BCAST31>(k);    if (t > k) k = t;
  return k;                                   // lane63 = wave max
}
__device__ __forceinline__ u64 bcast_key(u64 k, int srclane) {
  u32 lo = (u32)__builtin_amdgcn_readlane((int)(u32)(k & 0xFFFFFFFFull), srclane);
  u32 hi = (u32)__builtin_amdgcn_readlane((int)(u32)(k >> 32), srclane);
  return ((u64)hi << 32) | (u64)lo;
}
__device__ __forceinline__ float bcast_f32(float v, int srclane) {
  return __uint_as_float((u32)__builtin_amdgcn_readlane((int)__float_as_uint(v), srclane));
}

// ---- pruned in-register sim, NO barriers, identical on all waves ------
// (r6 verbatim; cert: t=0 always commits, t>=1 needs dist > cutd)
template<int NC>
__device__ __forceinline__ int sim_wave(const u32* s_pool, int m, u32 cutd,
    int jmax, int lane, float& ox, float& oy, float& oz) {
#pragma clang fp contract(off)
  u64 ck[NC]; float cx[NC], cy[NC], cz[NC];
#pragma unroll
  for (int i = 0; i < NC; ++i) {
    int idx = lane + i * 64;
    if (idx < m) {
      const u32* b = s_pool + idx * 5;
      ck[i] = ((u64)b[1] << 32) | (u64)b[0];
      cx[i] = __uint_as_float(b[2]); cy[i] = __uint_as_float(b[3]);
      cz[i] = __uint_as_float(b[4]);
    } else { ck[i] = 0; cx[i] = cy[i] = cz[i] = 0.f; }
  }
  int j = 0;
  for (int t = 0; t < jmax; ++t) {
    u64 tk = ck[0]; float mx = cx[0], my = cy[0], mz = cz[0];
#pragma unroll
    for (int i = 1; i < NC; ++i)
      if (ck[i] > tk) { tk = ck[i]; mx = cx[i]; my = cy[i]; mz = cz[i]; }
    u64 wk = bcast_key(dpp_max64_to63(tk), 63);
    if (t > 0 && (u32)(wk >> 32) <= cutd) break;   // not certified: stop
    int wl = __ffsll(__ballot(tk == wk)) - 1;
    float wx = bcast_f32(mx, wl), wy = bcast_f32(my, wl), wz = bcast_f32(mz, wl);
    if (lane == t) { ox = wx; oy = wy; oz = wz; }  // stash winner t
    j = t + 1;
#pragma unroll
    for (int i = 0; i < NC; ++i) {
      float dx = cx[i]-wx, dy = cy[i]-wy, dz = cz[i]-wz;
      float d2 = __fadd_rn(__fadd_rn(__fmul_rn(dx,dx), __fmul_rn(dy,dy)),
                           __fmul_rn(dz,dz));
      float nd = fminf(__uint_as_float((u32)(ck[i] >> 32)), d2);
      ck[i] = ((u64)__float_as_uint(nd) << 32) | (ck[i] & 0xFFFFFFFFull);
    }
  }
  return j;
}

__global__ __launch_bounds__(TPB, 1)
void fps_kernel(const float4* __restrict__ pts, float* __restrict__ out,
                u32* __restrict__ slots)
{
#pragma clang fp contract(off)
  const int batch = blockIdx.x >> 5;
  const int rank  = blockIdx.x & (NB - 1);
  const int tid   = threadIdx.x;
  const int lane  = tid & 63;
  const int wv    = tid >> 6;
  const int ws_id = rank * 4 + wv;           // wave-slot 0..127

  __shared__ u32   s_quads[NWAVE * 68];      // mirror, 68-u32 padded slots
  __shared__ u32   s_pool[NCAND * 5];        // pruned candidates
  __shared__ int   s_cnt2[2];                // ping-pong compact counters

  const float4* bpts = pts + (size_t)batch * NPB;
  u32* bslots = slots + (size_t)batch * (RING * RB_U32);
  const int base = rank * (TPB * PPT);

  float px[PPT], py[PPT], pz[PPT], dist[PPT];
  float4 seed = bpts[0];
  const float sx = seed.y, sy = seed.z, sz = seed.w;
#pragma unroll
  for (int k = 0; k < PPT; ++k) {
    float4 p = bpts[base + k * TPB + tid];   // row = (b, x, y, z)
    px[k] = p.y; py[k] = p.z; pz[k] = p.w;
    float dx = px[k]-sx, dy = py[k]-sy, dz = pz[k]-sz;
    dist[k] = __fadd_rn(__fadd_rn(__fmul_rn(dx,dx), __fmul_rn(dy,dy)),
                        __fmul_rn(dz,dz));   // == reference dist init
  }
  if (rank == 0 && tid == 0) {
    float4 o; o.x=(float)batch; o.y=sx; o.z=sy; o.w=sz;
    *(float4*)(out + (size_t)batch * MSAMP * 4) = o;
  }
  if (tid == 0) { s_cnt2[0] = 0; s_cnt2[1] = 0; }
  __syncthreads();

  int S = 0; u32 r = 0;
  float ox = 0.f, oy = 0.f, oz = 0.f;

  while (S < MSAMP - 1) {
    r += 1;
    const int rem = (MSAMP - 1) - S;
    const int jmax = (rem < JCAP) ? rem : JCAP;

    // ---- EXTRACT: wave top-8, pure DPP, no barriers (r6 verbatim) ----
    u32 mask = 0; u64 tk = 0; float tx=0.f, ty=0.f, tz=0.f; int tbk = 0;
#pragma unroll
    for (int k = 0; k < PPT; ++k) {
      u64 kk = ((u64)__float_as_uint(dist[k]) << 32) | ((u64)r << 17) |
               (u64)(0x1FFFF - (base + k * TPB + tid));
      if (kk > tk) { tk = kk; tx = px[k]; ty = py[k]; tz = pz[k]; tbk = k; }
    }
    u32x4 shipq;
    for (int c = 0; c < KW; ++c) {
      u64 wk = bcast_key(dpp_max64_to63(tk), 63);
      int wl = __ffsll(__ballot(tk == wk)) - 1;
      float wx = bcast_f32(tx, wl), wy = bcast_f32(ty, wl), wz = bcast_f32(tz, wl);
      if (lane == 2*c)     { shipq.x=(u32)(wk & 0xFFFFFFFFull); shipq.y=(u32)(wk>>32);
                             shipq.z=__float_as_uint(wx); shipq.w=__float_as_uint(wy); }
      if (lane == 2*c + 1) { shipq.x=r; shipq.y=__float_as_uint(wz);
                             shipq.z=0u; shipq.w=0u; }
      if (tk == wk) {                        // my point won: mask + rescan
        mask |= 1u << tbk;
        tk = 0; tx = ty = tz = 0.f; tbk = 0;
#pragma unroll
        for (int k = 0; k < PPT; ++k) {
          if (!((mask >> k) & 1u)) {
            u64 kk = ((u64)__float_as_uint(dist[k]) << 32) | ((u64)r << 17) |
                     (u64)(0x1FFFF - (base + k * TPB + tid));
            if (kk > tk) { tk = kk; tx = px[k]; ty = py[k]; tz = pz[k]; tbk = k; }
          }
        }
      }
    }

    // ---- SHIP: wave stores its 16 quads immediately ----
    u32* ring = bslots + (size_t)(r & (RING - 1)) * RB_U32;
    if (lane < 16) st16_sys(ring + (ws_id * 16 + lane) * 4, shipq);

    // ---- POLL: my wave's 512-quad quarter, 8 loads / lane, one RT ----
    const int gb = wv * 512 + lane;
    const u32 *pp0 = ring + (gb      ) * 4, *pp1 = ring + (gb +  64) * 4,
              *pp2 = ring + (gb + 128) * 4, *pp3 = ring + (gb + 192) * 4,
              *pp4 = ring + (gb + 256) * 4, *pp5 = ring + (gb + 320) * 4,
              *pp6 = ring + (gb + 384) * 4, *pp7 = ring + (gb + 448) * 4;
    u32x4 q0,q1,q2,q3,q4,q5,q6,q7;
    for (u32 it = 0; ; ++it) {
      ld16x8_sys(pp0,pp1,pp2,pp3,pp4,pp5,pp6,pp7, q0,q1,q2,q3,q4,q5,q6,q7);
      bool ok;
      if ((lane & 1) == 0)
        ok = ((q0.x>>17)==r)&&((q1.x>>17)==r)&&((q2.x>>17)==r)&&((q3.x>>17)==r)&&
             ((q4.x>>17)==r)&&((q5.x>>17)==r)&&((q6.x>>17)==r)&&((q7.x>>17)==r);
      else
        ok = (q0.x==r)&&(q1.x==r)&&(q2.x==r)&&(q3.x==r)&&
             (q4.x==r)&&(q5.x==r)&&(q6.x==r)&&(q7.x==r);
      if (__ballot(ok) == ~0ull) break;
      __builtin_amdgcn_s_sleep(1);
    }
    // reset NEXT round's compact counter (safe: ordered by mirror barriers)
    if (tid == 0) s_cnt2[(r + 1) & 1] = 0;
    // mirror my 8 quads to LDS (padded slots: 68 u32 / wave-slot)
    {
      int g = gb;
      *(u32x4*)&s_quads[(g>>4)*68 + (g&15)*4] = q0; g += 64;
      *(u32x4*)&s_quads[(g>>4)*68 + (g&15)*4] = q1; g += 64;
      *(u32x4*)&s_quads[(g>>4)*68 + (g&15)*4] = q2; g += 64;
      *(u32x4*)&s_quads[(g>>4)*68 + (g&15)*4] = q3; g += 64;
      *(u32x4*)&s_quads[(g>>4)*68 + (g&15)*4] = q4; g += 64;
      *(u32x4*)&s_quads[(g>>4)*68 + (g&15)*4] = q5; g += 64;
      *(u32x4*)&s_quads[(g>>4)*68 + (g&15)*4] = q6; g += 64;
      *(u32x4*)&s_quads[(g>>4)*68 + (g&15)*4] = q7;
    }
    __syncthreads();                         // barrier 1: all 2048 in LDS

    // ---- CUTOFF: max over 128 wave-8th keys (per wave, no barrier) ----
    u64 cutk;
    {
      int w0 = lane, w1 = lane + 64;
      u64 k0 = ((u64)s_quads[w0*68 + 57] << 32) | (u64)s_quads[w0*68 + 56];
      u64 k1 = ((u64)s_quads[w1*68 + 57] << 32) | (u64)s_quads[w1*68 + 56];
      u64 ct = (k0 > k1) ? k0 : k1;
      cutk = bcast_key(dpp_max64_to63(ct), 63);
    }
    const u32 cutd = (u32)(cutk >> 32);

    // ---- PRUNE: wave-aggregated (ballot offsets + 1 atomic/wave) ----
    int* cnt = &s_cnt2[r & 1];
    bool hh[4]; int myoff[4]; int tot = 0;
    u32 clo[4], chi[4], cx4[4], cy4[4], cz4[4];
    const u64 ltmask = (1ull << lane) - 1ull;
#pragma unroll
    for (int i = 0; i < 4; ++i) {
      int cg = tid * 4 + i;
      int qb = (cg >> 3) * 68 + (cg & 7) * 8;
      u32 lo = s_quads[qb], hi = s_quads[qb + 1];
      u64 kk = ((u64)hi << 32) | (u64)lo;
      clo[i] = lo; chi[i] = hi;
      cx4[i] = s_quads[qb+2]; cy4[i] = s_quads[qb+3]; cz4[i] = s_quads[qb+5];
      hh[i] = kk > cutk;
      u64 b = __ballot(hh[i]);
      myoff[i] = tot + __popcll(b & ltmask);
      tot += __popcll(b);
    }
    int pbase = 0;
    if (lane == 0) pbase = atomicAdd(cnt, tot);
    pbase = __builtin_amdgcn_readfirstlane(pbase);
#pragma unroll
    for (int i = 0; i < 4; ++i)
      if (hh[i]) {
        u32* d = &s_pool[(pbase + myoff[i]) * 5];
        d[0]=clo[i]; d[1]=chi[i]; d[2]=cx4[i]; d[3]=cy4[i]; d[4]=cz4[i];
      }
    __syncthreads();                         // barrier 2: pool + m final
    const int m = *cnt;                      // m <= 128*7 = 896 (proven)

    // ---- SIM: wave-register tiers only (change A; NC=14 covers 896) ----
    int j;
    if      (m <=  64) j = sim_wave<1>(s_pool, m, cutd, jmax, lane, ox, oy, oz);
    else if (m <= 128) j = sim_wave<2>(s_pool, m, cutd, jmax, lane, ox, oy, oz);
    else if (m <= 256) j = sim_wave<4>(s_pool, m, cutd, jmax, lane, ox, oy, oz);
    else if (m <= 512) j = sim_wave<8>(s_pool, m, cutd, jmax, lane, ox, oy, oz);
    else               j = sim_wave<14>(s_pool, m, cutd, jmax, lane, ox, oy, oz);

    // ---- COMMIT: output rows + batched register dist update ----
    if (rank == 0 && wv == 0 && lane < j) {
      float4 o; o.x = (float)batch; o.y = ox; o.z = oy; o.w = oz;
      *(float4*)(out + (size_t)(batch * MSAMP + S + 1 + lane) * 4) = o;
    }
    for (int i = 0; i < j; ++i) {            // ascending = reference order
      float wx = bcast_f32(ox, i), wy = bcast_f32(oy, i), wz = bcast_f32(oz, i);
#pragma unroll
      for (int k = 0; k < PPT; ++k) {
        float dx = px[k]-wx, dy = py[k]-wy, dz = pz[k]-wz;
        float d2 = __fadd_rn(__fadd_rn(__fmul_rn(dx,dx), __fmul_rn(dy,dy)),
                             __fmul_rn(dz,dz));
        dist[k] = fminf(dist[k], d2);
      }
    }
    S += j;
  }
}

extern "C" void kernel_launch(void* const* d_in, const int* in_sizes, int n_in,
                              void* d_out, int out_size, void* d_ws, size_t ws_size,
                              hipStream_t stream) {
  const float4* pts = (const float4*)d_in[0];
  float* out = (float*)d_out;
  u32* slots = (u32*)d_ws;

  // Zero both batches' rings (128 KB): stale tags can never validate.
  hipMemsetAsync(d_ws, 0, (size_t)2 * RING * RB_U32 * 4, stream);

  dim3 grid(2 * NB), block(TPB);
  hipLaunchKernelGGL(fps_kernel, grid, block, 0, stream, pts, out, slots);
}